// Round 13
// baseline (2154.506 us; speedup 1.0000x reference)
//
#include <hip/hip_runtime.h>
#include <math.h>

#define T_SEQ 512
#define B_SZ  64
#define I_DIM 512
#define H_DIM 1024

typedef __attribute__((ext_vector_type(8))) short     short8;
typedef __attribute__((ext_vector_type(4))) float     f32x4;

// ---------------- recurrence LDS geometry (carved from dynamic smem) ----------------
#define HROW   1040                      // staged h row stride in shorts: 2080 B = 520 banks
                                         // = 8 banks/row -> A-read b128 2-way (free), was 4-way
#define HPLANE (8 * HROW)                // single h plane, 8 batches -> 16640 B
#define RED_OFF HPLANE                   // red[2] after the plane (short index)
#define RECUR_LDS_BYTES 148096           // forces 1 block/CU; ~33 KB used
#define RING 4                           // h ring slots (K>=2 proven safe)

// ---------------- xw MFMA GEMM geometry ----------------
#define XKP 40                           // padded k-row stride (shorts)

__device__ __forceinline__ unsigned short f2bf_rn(float f) {
    unsigned u = __float_as_uint(f);
    unsigned r = u + 0x7fffu + ((u >> 16) & 1u);
    return (unsigned short)(r >> 16);
}
__device__ __forceinline__ float bf2f(unsigned short s) {
    return __uint_as_float(((unsigned)s) << 16);
}

// =====================================================================
// Kernel 0: split fp32 matrix -> bf16 hi/lo planes (one-time prep)
// =====================================================================
__global__ __launch_bounds__(256) void wsplit_kernel(
    const float* __restrict__ W, unsigned short* __restrict__ Whi,
    unsigned short* __restrict__ Wlo, int n)
{
    int i = blockIdx.x * 256 + threadIdx.x;
    if (i < n) {
        float w = W[i];
        unsigned short hi = f2bf_rn(w);
        Whi[i] = hi;
        Wlo[i] = f2bf_rn(w - bf2f(hi));
    }
}

// =====================================================================
// Kernel 1: MFMA xw GEMM (proven round 9)
// =====================================================================
__global__ __launch_bounds__(256) void xw_mfma_kernel(
    const float* __restrict__ input,         // [64][512][512] fp32
    const unsigned short* __restrict__ Whi,  // [1024][512] bf16 hi
    const unsigned short* __restrict__ Wlo,  // [1024][512] bf16 lo
    const float* __restrict__ b_ih,          // [1024]
    float* __restrict__ xw,                  // [tc][64][1024] fp32
    int t0, int ntch)
{
    __shared__ short xhi[128 * XKP];
    __shared__ short xlo[128 * XKP];
    __shared__ short whi[128 * XKP];
    __shared__ short wlo[128 * XKP];

    const int tid = threadIdx.x;
    const int per = 64 * ntch;
    const int grp = blockIdx.x % per;
    const int hch = blockIdx.x / per;
    const int b   = grp & 63;
    const int tch = grp >> 6;
    const int n0  = hch * 128;
    const int w   = tid >> 6;
    const int l   = tid & 63;

    const float* xsrc = input + ((size_t)b * T_SEQ + t0 + tch * 128) * I_DIM;
    const unsigned short* whsrc = Whi + (size_t)n0 * I_DIM;
    const unsigned short* wlsrc = Wlo + (size_t)n0 * I_DIM;

    f32x4 acc[8][2] = {};

    const int srow = tid >> 1;         // 0..127
    const int skq  = (tid & 1) * 16;   // 0 or 16

    for (int kt = 0; kt < I_DIM; kt += 32) {
        {
            const float* p = xsrc + (size_t)srow * I_DIM + kt + skq;
            union S8 { short s[8]; short8 v; };
            S8 h0, h1, l0, l1;
            #pragma unroll
            for (int i = 0; i < 8; ++i) {
                float f = p[i];
                unsigned short hh = f2bf_rn(f);
                h0.s[i] = (short)hh; l0.s[i] = (short)f2bf_rn(f - bf2f(hh));
            }
            #pragma unroll
            for (int i = 0; i < 8; ++i) {
                float f = p[8 + i];
                unsigned short hh = f2bf_rn(f);
                h1.s[i] = (short)hh; l1.s[i] = (short)f2bf_rn(f - bf2f(hh));
            }
            *(short8*)&xhi[srow * XKP + skq]     = h0.v;
            *(short8*)&xhi[srow * XKP + skq + 8] = h1.v;
            *(short8*)&xlo[srow * XKP + skq]     = l0.v;
            *(short8*)&xlo[srow * XKP + skq + 8] = l1.v;
        }
        {
            const unsigned short* ph = whsrc + (size_t)srow * I_DIM + kt + skq;
            const unsigned short* pl = wlsrc + (size_t)srow * I_DIM + kt + skq;
            *(short8*)&whi[srow * XKP + skq]     = *(const short8*)(ph);
            *(short8*)&whi[srow * XKP + skq + 8] = *(const short8*)(ph + 8);
            *(short8*)&wlo[srow * XKP + skq]     = *(const short8*)(pl);
            *(short8*)&wlo[srow * XKP + skq + 8] = *(const short8*)(pl + 8);
        }
        __syncthreads();

        short8 bh[2], bl[2];
        #pragma unroll
        for (int ni = 0; ni < 2; ++ni) {
            int brow = w * 32 + ni * 16 + (l & 15);
            bh[ni] = *(const short8*)&whi[brow * XKP + (l >> 4) * 8];
            bl[ni] = *(const short8*)&wlo[brow * XKP + (l >> 4) * 8];
        }
        #pragma unroll
        for (int mi = 0; mi < 8; ++mi) {
            int arow = mi * 16 + (l & 15);
            short8 ah = *(const short8*)&xhi[arow * XKP + (l >> 4) * 8];
            short8 al = *(const short8*)&xlo[arow * XKP + (l >> 4) * 8];
            #pragma unroll
            for (int ni = 0; ni < 2; ++ni) {
                acc[mi][ni] = __builtin_amdgcn_mfma_f32_16x16x32_bf16(ah, bh[ni], acc[mi][ni], 0, 0, 0);
                acc[mi][ni] = __builtin_amdgcn_mfma_f32_16x16x32_bf16(al, bh[ni], acc[mi][ni], 0, 0, 0);
                acc[mi][ni] = __builtin_amdgcn_mfma_f32_16x16x32_bf16(ah, bl[ni], acc[mi][ni], 0, 0, 0);
            }
        }
        __syncthreads();
    }

    const int tb = tch * 128;
    #pragma unroll
    for (int ni = 0; ni < 2; ++ni) {
        int col = n0 + w * 32 + ni * 16 + (l & 15);
        float bias = b_ih[col];
        #pragma unroll
        for (int mi = 0; mi < 8; ++mi)
            #pragma unroll
            for (int r = 0; r < 4; ++r) {
                int s = tb + mi * 16 + (l >> 4) * 4 + r;
                xw[((size_t)s * B_SZ + b) * H_DIM + col] = acc[mi][ni][r] + bias;
            }
    }
}

// =====================================================================
// Kernel 1b (fallback for small ws): VALU xw GEMM (proven rounds 2-8)
// =====================================================================
__global__ __launch_bounds__(256) void xw_gemm_kernel(
    const float* __restrict__ input, const float* __restrict__ W_ih,
    const float* __restrict__ b_ih, float* __restrict__ xw,
    int t0)
{
    __shared__ float Ash[32 * 68];
    __shared__ float Bsh[32 * 68];

    const int bm  = blockIdx.x >> 4;
    const int bn  = blockIdx.x & 15;
    const int tid = threadIdx.x;
    const int tx  = tid & 15;
    const int ty  = tid >> 4;

    const int t = t0 + bm;
    const float* Abase = input + (size_t)t * I_DIM;
    const float* Bbase = W_ih + (size_t)(bn * 64) * I_DIM;

    float acc[4][4] = {};

    for (int kt = 0; kt < I_DIM; kt += 32) {
        #pragma unroll
        for (int p = 0; p < 2; ++p) {
            int idx = tid + p * 256;
            int row = idx >> 3;
            int c4  = (idx & 7) << 2;
            float4 a = *(const float4*)(Abase + (size_t)row * (T_SEQ * I_DIM) + kt + c4);
            float4 b = *(const float4*)(Bbase + (size_t)row * I_DIM + kt + c4);
            Ash[(c4 + 0) * 68 + row] = a.x; Ash[(c4 + 1) * 68 + row] = a.y;
            Ash[(c4 + 2) * 68 + row] = a.z; Ash[(c4 + 3) * 68 + row] = a.w;
            Bsh[(c4 + 0) * 68 + row] = b.x; Bsh[(c4 + 1) * 68 + row] = b.y;
            Bsh[(c4 + 2) * 68 + row] = b.z; Bsh[(c4 + 3) * 68 + row] = b.w;
        }
        __syncthreads();
        #pragma unroll
        for (int k = 0; k < 32; ++k) {
            float4 a4 = *(const float4*)&Ash[k * 68 + ty * 4];
            float4 b4 = *(const float4*)&Bsh[k * 68 + tx * 4];
            float av[4] = {a4.x, a4.y, a4.z, a4.w};
            float bv[4] = {b4.x, b4.y, b4.z, b4.w};
            #pragma unroll
            for (int i = 0; i < 4; ++i)
                #pragma unroll
                for (int j = 0; j < 4; ++j)
                    acc[i][j] += av[i] * bv[j];
        }
        __syncthreads();
    }

    const int ncol = bn * 64 + tx * 4;
    float4 bias = *(const float4*)(b_ih + ncol);
    #pragma unroll
    for (int i = 0; i < 4; ++i) {
        int b = ty * 4 + i;
        float4 v;
        v.x = acc[i][0] + bias.x; v.y = acc[i][1] + bias.y;
        v.z = acc[i][2] + bias.z; v.w = acc[i][3] + bias.w;
        *(float4*)(xw + ((size_t)bm * B_SZ + b) * H_DIM + ncol) = v;
    }
}

// =====================================================================
// Kernel 2: persistent MFMA recurrence — FIRE-AND-FORGET publish +
// per-wave MERGED detect/fetch (tag-in-data poll at chunk granularity).
//  vs R12: no sentinel, no producer barrier/drain. Publish = one sc1
//  h-store + nontemporal out store; the data IS the signal. Each wave
//  polls its 8 producer chunks (1 KB each) directly: first iteration is
//  the fetch itself; re-polls reload only still-stale chunks. One block
//  barrier per step remains (B2, partial reduction); red[] is double-
//  buffered by step parity to replace the removed barrier's separation
//  (adjacent steps use different halves; same-parity steps are ordered
//  through the shared B2 barrier). Correctness gates unchanged: tag-
//  verified consumption, RING=4 overwrite-safety chain, replay value-
//  determinism.
// =====================================================================
__global__ __launch_bounds__(256, 1) void elman_recur_kernel(
    const float* __restrict__ xw,            // [tc][64][1024]
    const unsigned short* __restrict__ Whi,  // [1024][1024] bf16 hi plane
    const unsigned short* __restrict__ Wlo,  // [1024][1024] bf16 lo plane
    unsigned int* __restrict__ hbuf,         // [RING][64][1024] tagged words
    float* __restrict__ out,                 // [64][512][1024]
    int t0, int tc)
{
    extern __shared__ __align__(16) short smem[];
    short* hA   = smem;                       // [8][HROW] bf16 (single plane)
    float* redb = (float*)(smem + RED_OFF);   // [2][4][2][16][16]

    const int tid = threadIdx.x;
    const int bg  = blockIdx.x & 7;     // batch group
    const int js  = blockIdx.x >> 3;    // j slice
    const int w   = tid >> 6;           // wave id (K-split)
    const int l   = tid & 63;           // lane
    const int b   = tid & 7;            // epilogue: batch
    const int jl  = tid >> 3;           // epilogue: local j (0..31)
    const int jg  = js * 32 + jl;
    const int bgl = bg * 8 + b;

    // ---- one-time: W B-fragments into registers (k-contiguous, B^T layout) ----
    short8 Bhi[2][8], Blo[2][8];
    {
        const int n  = l & 15;
        const int kb = (l >> 4) * 8;
        #pragma unroll
        for (int t2 = 0; t2 < 2; ++t2) {
            const unsigned short* rhi = Whi + (size_t)(js * 32 + t2 * 16 + n) * H_DIM;
            const unsigned short* rlo = Wlo + (size_t)(js * 32 + t2 * 16 + n) * H_DIM;
            #pragma unroll
            for (int ks = 0; ks < 8; ++ks) {
                int k = w * 256 + ks * 32 + kb;
                Bhi[t2][ks] = *(const short8*)(rhi + k);
                Blo[t2][ks] = *(const short8*)(rlo + k);
            }
        }
    }

    for (int s = 0; s < tc; ++s) {
        const int t = t0 + s;
        float* red = redb + (s & 1) * (4 * 2 * 16 * 16);   // parity buffer

        // prefetch xw (independent of h) before any waiting
        float pre = xw[((size_t)s * B_SZ + bgl) * H_DIM + jg];

        if (t > 0) {
            const unsigned tagw = (unsigned)(t - 1);
            const unsigned long long* grp = (const unsigned long long*)
                (hbuf + (size_t)((t - 1) & (RING - 1)) * B_SZ * H_DIM
                      + (size_t)bg * 8 * H_DIM);

            // ---- merged detect+fetch: poll my 8 producer chunks directly.
            //      First iteration IS the data fetch; re-load only stale
            //      chunks. stale stays wave-uniform (updated via __all). ----
            unsigned long long v[8][2];
            unsigned stale = 0xffu;
            do {
                #pragma unroll
                for (int p = 0; p < 8; ++p) {
                    if (stale & (1u << p)) {
                        v[p][0] = __hip_atomic_load(grp + p * 512 + w * 128 + l,
                                                    __ATOMIC_RELAXED,
                                                    __HIP_MEMORY_SCOPE_AGENT);
                        v[p][1] = __hip_atomic_load(grp + p * 512 + w * 128 + 64 + l,
                                                    __ATOMIC_RELAXED,
                                                    __HIP_MEMORY_SCOPE_AGENT);
                    }
                }
                #pragma unroll
                for (int p = 0; p < 8; ++p) {
                    if (stale & (1u << p)) {
                        int ok = (((unsigned)(v[p][0] >> 16) & 0xffffu) == tagw);
                        ok &= ((unsigned)(v[p][0] >> 48) == tagw);
                        ok &= (((unsigned)(v[p][1] >> 16) & 0xffffu) == tagw);
                        ok &= ((unsigned)(v[p][1] >> 48) == tagw);
                        if (__all(ok)) stale &= ~(1u << p);
                    }
                }
            } while (stale);

            // ---- unpack payloads -> my hA column slice (wave-local LDS) ----
            #pragma unroll
            for (int p = 0; p < 8; ++p)
                #pragma unroll
                for (int i = 0; i < 2; ++i) {
                    int c = w * 256 + i * 128 + l * 2;
                    unsigned lo32 = (unsigned)v[p][i];
                    unsigned hi32 = (unsigned)(v[p][i] >> 32);
                    *(unsigned*)(hA + p * HROW + c) = (lo32 & 0xffffu) | (hi32 << 16);
                }
            // no block barrier: each wave reads only columns it wrote
            // (ds write->read ordering is wave-local via lgkmcnt)

            // ---- MFMA: this wave's K range, 2 N-tiles, 2 passes (Whi+Wlo) ----
            f32x4 acc0 = {0.f, 0.f, 0.f, 0.f};
            f32x4 acc1 = {0.f, 0.f, 0.f, 0.f};
            const short* aAb = hA + (l & 7) * HROW + w * 256 + ((l >> 4) * 8);
            #pragma unroll
            for (int ks = 0; ks < 8; ++ks) {
                short8 ah = *(const short8*)(aAb + ks * 32);
                acc0 = __builtin_amdgcn_mfma_f32_16x16x32_bf16(ah, Bhi[0][ks], acc0, 0, 0, 0);
                acc1 = __builtin_amdgcn_mfma_f32_16x16x32_bf16(ah, Bhi[1][ks], acc1, 0, 0, 0);
                acc0 = __builtin_amdgcn_mfma_f32_16x16x32_bf16(ah, Blo[0][ks], acc0, 0, 0, 0);
                acc1 = __builtin_amdgcn_mfma_f32_16x16x32_bf16(ah, Blo[1][ks], acc1, 0, 0, 0);
            }
            // partials -> LDS  (D layout: col = l&15, row = (l>>4)*4 + reg)
            *(f32x4*)&red[((w * 2 + 0) * 16 + (l & 15)) * 16 + (l >> 4) * 4] = acc0;
            *(f32x4*)&red[((w * 2 + 1) * 16 + (l & 15)) * 16 + (l >> 4) * 4] = acc1;
            __syncthreads();   // B2: all waves' partials visible

            // reduce 4 wave-partials for this thread's (b, jl)
            const int tt = jl >> 4, c = jl & 15;
            #pragma unroll
            for (int w2 = 0; w2 < 4; ++w2)
                pre += red[((w2 * 2 + tt) * 16 + c) * 16 + b];
        }

        float hval = tanhf(pre);

        // fire-and-forget publish: the tagged store IS the completion signal
        unsigned packed = ((unsigned)t << 16) | (unsigned)f2bf_rn(hval);
        __hip_atomic_store(hbuf + (size_t)(t & (RING - 1)) * B_SZ * H_DIM
                                + (size_t)bgl * H_DIM + jg,
                           packed, __ATOMIC_RELAXED, __HIP_MEMORY_SCOPE_AGENT);
        __builtin_nontemporal_store(hval, out + ((size_t)bgl * T_SEQ + t) * H_DIM + jg);
        // no drain, no barrier, no sentinel — consumer tag-poll validates
    }
}

// =====================================================================
extern "C" void kernel_launch(void* const* d_in, const int* in_sizes, int n_in,
                              void* d_out, int out_size, void* d_ws, size_t ws_size,
                              hipStream_t stream) {
    (void)in_sizes; (void)n_in; (void)out_size;
    const float* input = (const float*)d_in[0];   // [64,512,512]
    const float* W_ih  = (const float*)d_in[1];   // [1024,512]
    const float* b_ih  = (const float*)d_in[2];   // [1024]
    const float* W_hh  = (const float*)d_in[3];   // [1024,1024]
    float* out = (float*)d_out;

    char* ws = (char*)d_ws;
    // layout: hbuf ring 1M | (reserved 64K) | Whh hi 2M | Whh lo 2M |
    //         Wih hi 1M | Wih lo 1M | xw ...
    unsigned int*   hbuf   = (unsigned int*)ws;
    unsigned short* Whh_hi = (unsigned short*)(ws + (1 << 20) + (64 << 10));
    unsigned short* Whh_lo = (unsigned short*)(ws + (3 << 20) + (64 << 10));
    unsigned short* Wih_hi = (unsigned short*)(ws + (5 << 20) + (64 << 10));
    unsigned short* Wih_lo = (unsigned short*)(ws + (6 << 20) + (64 << 10));
    const size_t    xw_off = (size_t)(7 << 20) + (64 << 10);
    float*          xwbuf  = (float*)(ws + xw_off);

    const size_t slice_bytes = (size_t)B_SZ * H_DIM * sizeof(float);  // 256 KB/t
    size_t avail = ws_size > xw_off ? ws_size - xw_off : 0;
    int Tc = (int)(avail / slice_bytes);
    if (Tc > T_SEQ) Tc = T_SEQ;
    bool mfma_xw = (Tc >= 128);
    if (mfma_xw) Tc &= ~127;          // multiple of 128 for the tiled GEMM
    if (Tc < 1)  Tc = 1;

    hipFuncSetAttribute((const void*)elman_recur_kernel,
                        hipFuncAttributeMaxDynamicSharedMemorySize,
                        RECUR_LDS_BYTES);

    // one-time splits (stream-ordered)
    wsplit_kernel<<<dim3(4096), dim3(256), 0, stream>>>(
        W_hh, Whh_hi, Whh_lo, H_DIM * H_DIM);
    wsplit_kernel<<<dim3(2048), dim3(256), 0, stream>>>(
        W_ih, Wih_hi, Wih_lo, H_DIM * I_DIM);

    for (int t0 = 0; t0 < T_SEQ; t0 += Tc) {
        int tc = (T_SEQ - t0 < Tc) ? (T_SEQ - t0) : Tc;

        if (mfma_xw && (tc % 128) == 0) {
            int ntch = tc / 128;
            xw_mfma_kernel<<<dim3(8 * 64 * ntch), dim3(256), 0, stream>>>(
                input, Wih_hi, Wih_lo, b_ih, xwbuf, t0, ntch);
        } else {
            xw_gemm_kernel<<<dim3((unsigned)tc * 16), dim3(256), 0, stream>>>(
                input, W_ih, b_ih, xwbuf, t0);
        }

        // plain launch (graph-capture-safe, proven): 148 KB LDS -> 1 block/CU,
        // grid 256 == CU count -> co-resident.
        elman_recur_kernel<<<dim3(256), dim3(256), RECUR_LDS_BYTES, stream>>>(
            xwbuf, Whh_hi, Whh_lo, hbuf, out, t0, tc);
    }
}

// Round 14
// 1283.292 us; speedup vs baseline: 1.6789x; 1.6789x over previous
//
#include <hip/hip_runtime.h>
#include <math.h>

#define T_SEQ 512
#define B_SZ  64
#define I_DIM 512
#define H_DIM 1024

typedef __attribute__((ext_vector_type(8))) short     short8;
typedef __attribute__((ext_vector_type(4))) float     f32x4;

// ---------------- recurrence LDS geometry (carved from dynamic smem) ----------------
#define HROW   1040                      // staged h row stride in shorts: 2080 B -> 8-bank row
                                         // offset; A-read ds_read_b128 2-way (free), was 4-way
#define HPLANE (8 * HROW)                // single h plane, 8 batches -> 16640 B
#define RED_OFF HPLANE                   // red[] after the plane (short index)
#define RECUR_LDS_BYTES 148096           // forces 1 block/CU; ~35 KB used
#define RING 4                           // h ring slots (K>=2 proven safe)

// ---------------- xw MFMA GEMM geometry ----------------
#define XKP 40                           // padded k-row stride (shorts)

__device__ __forceinline__ unsigned short f2bf_rn(float f) {
    unsigned u = __float_as_uint(f);
    unsigned r = u + 0x7fffu + ((u >> 16) & 1u);
    return (unsigned short)(r >> 16);
}
__device__ __forceinline__ float bf2f(unsigned short s) {
    return __uint_as_float(((unsigned)s) << 16);
}

// =====================================================================
// Kernel 0: split fp32 matrix -> bf16 hi/lo planes (one-time prep)
// =====================================================================
__global__ __launch_bounds__(256) void wsplit_kernel(
    const float* __restrict__ W, unsigned short* __restrict__ Whi,
    unsigned short* __restrict__ Wlo, int n)
{
    int i = blockIdx.x * 256 + threadIdx.x;
    if (i < n) {
        float w = W[i];
        unsigned short hi = f2bf_rn(w);
        Whi[i] = hi;
        Wlo[i] = f2bf_rn(w - bf2f(hi));
    }
}

// =====================================================================
// Kernel 1: MFMA xw GEMM (proven round 9)
// =====================================================================
__global__ __launch_bounds__(256) void xw_mfma_kernel(
    const float* __restrict__ input,         // [64][512][512] fp32
    const unsigned short* __restrict__ Whi,  // [1024][512] bf16 hi
    const unsigned short* __restrict__ Wlo,  // [1024][512] bf16 lo
    const float* __restrict__ b_ih,          // [1024]
    float* __restrict__ xw,                  // [tc][64][1024] fp32
    int t0, int ntch)
{
    __shared__ short xhi[128 * XKP];
    __shared__ short xlo[128 * XKP];
    __shared__ short whi[128 * XKP];
    __shared__ short wlo[128 * XKP];

    const int tid = threadIdx.x;
    const int per = 64 * ntch;
    const int grp = blockIdx.x % per;
    const int hch = blockIdx.x / per;
    const int b   = grp & 63;
    const int tch = grp >> 6;
    const int n0  = hch * 128;
    const int w   = tid >> 6;
    const int l   = tid & 63;

    const float* xsrc = input + ((size_t)b * T_SEQ + t0 + tch * 128) * I_DIM;
    const unsigned short* whsrc = Whi + (size_t)n0 * I_DIM;
    const unsigned short* wlsrc = Wlo + (size_t)n0 * I_DIM;

    f32x4 acc[8][2] = {};

    const int srow = tid >> 1;         // 0..127
    const int skq  = (tid & 1) * 16;   // 0 or 16

    for (int kt = 0; kt < I_DIM; kt += 32) {
        {
            const float* p = xsrc + (size_t)srow * I_DIM + kt + skq;
            union S8 { short s[8]; short8 v; };
            S8 h0, h1, l0, l1;
            #pragma unroll
            for (int i = 0; i < 8; ++i) {
                float f = p[i];
                unsigned short hh = f2bf_rn(f);
                h0.s[i] = (short)hh; l0.s[i] = (short)f2bf_rn(f - bf2f(hh));
            }
            #pragma unroll
            for (int i = 0; i < 8; ++i) {
                float f = p[8 + i];
                unsigned short hh = f2bf_rn(f);
                h1.s[i] = (short)hh; l1.s[i] = (short)f2bf_rn(f - bf2f(hh));
            }
            *(short8*)&xhi[srow * XKP + skq]     = h0.v;
            *(short8*)&xhi[srow * XKP + skq + 8] = h1.v;
            *(short8*)&xlo[srow * XKP + skq]     = l0.v;
            *(short8*)&xlo[srow * XKP + skq + 8] = l1.v;
        }
        {
            const unsigned short* ph = whsrc + (size_t)srow * I_DIM + kt + skq;
            const unsigned short* pl = wlsrc + (size_t)srow * I_DIM + kt + skq;
            *(short8*)&whi[srow * XKP + skq]     = *(const short8*)(ph);
            *(short8*)&whi[srow * XKP + skq + 8] = *(const short8*)(ph + 8);
            *(short8*)&wlo[srow * XKP + skq]     = *(const short8*)(pl);
            *(short8*)&wlo[srow * XKP + skq + 8] = *(const short8*)(pl + 8);
        }
        __syncthreads();

        short8 bh[2], bl[2];
        #pragma unroll
        for (int ni = 0; ni < 2; ++ni) {
            int brow = w * 32 + ni * 16 + (l & 15);
            bh[ni] = *(const short8*)&whi[brow * XKP + (l >> 4) * 8];
            bl[ni] = *(const short8*)&wlo[brow * XKP + (l >> 4) * 8];
        }
        #pragma unroll
        for (int mi = 0; mi < 8; ++mi) {
            int arow = mi * 16 + (l & 15);
            short8 ah = *(const short8*)&xhi[arow * XKP + (l >> 4) * 8];
            short8 al = *(const short8*)&xlo[arow * XKP + (l >> 4) * 8];
            #pragma unroll
            for (int ni = 0; ni < 2; ++ni) {
                acc[mi][ni] = __builtin_amdgcn_mfma_f32_16x16x32_bf16(ah, bh[ni], acc[mi][ni], 0, 0, 0);
                acc[mi][ni] = __builtin_amdgcn_mfma_f32_16x16x32_bf16(al, bh[ni], acc[mi][ni], 0, 0, 0);
                acc[mi][ni] = __builtin_amdgcn_mfma_f32_16x16x32_bf16(ah, bl[ni], acc[mi][ni], 0, 0, 0);
            }
        }
        __syncthreads();
    }

    const int tb = tch * 128;
    #pragma unroll
    for (int ni = 0; ni < 2; ++ni) {
        int col = n0 + w * 32 + ni * 16 + (l & 15);
        float bias = b_ih[col];
        #pragma unroll
        for (int mi = 0; mi < 8; ++mi)
            #pragma unroll
            for (int r = 0; r < 4; ++r) {
                int s = tb + mi * 16 + (l >> 4) * 4 + r;
                xw[((size_t)s * B_SZ + b) * H_DIM + col] = acc[mi][ni][r] + bias;
            }
    }
}

// =====================================================================
// Kernel 1b (fallback for small ws): VALU xw GEMM (proven rounds 2-8)
// =====================================================================
__global__ __launch_bounds__(256) void xw_gemm_kernel(
    const float* __restrict__ input, const float* __restrict__ W_ih,
    const float* __restrict__ b_ih, float* __restrict__ xw,
    int t0)
{
    __shared__ float Ash[32 * 68];
    __shared__ float Bsh[32 * 68];

    const int bm  = blockIdx.x >> 4;
    const int bn  = blockIdx.x & 15;
    const int tid = threadIdx.x;
    const int tx  = tid & 15;
    const int ty  = tid >> 4;

    const int t = t0 + bm;
    const float* Abase = input + (size_t)t * I_DIM;
    const float* Bbase = W_ih + (size_t)(bn * 64) * I_DIM;

    float acc[4][4] = {};

    for (int kt = 0; kt < I_DIM; kt += 32) {
        #pragma unroll
        for (int p = 0; p < 2; ++p) {
            int idx = tid + p * 256;
            int row = idx >> 3;
            int c4  = (idx & 7) << 2;
            float4 a = *(const float4*)(Abase + (size_t)row * (T_SEQ * I_DIM) + kt + c4);
            float4 b = *(const float4*)(Bbase + (size_t)row * I_DIM + kt + c4);
            Ash[(c4 + 0) * 68 + row] = a.x; Ash[(c4 + 1) * 68 + row] = a.y;
            Ash[(c4 + 2) * 68 + row] = a.z; Ash[(c4 + 3) * 68 + row] = a.w;
            Bsh[(c4 + 0) * 68 + row] = b.x; Bsh[(c4 + 1) * 68 + row] = b.y;
            Bsh[(c4 + 2) * 68 + row] = b.z; Bsh[(c4 + 3) * 68 + row] = b.w;
        }
        __syncthreads();
        #pragma unroll
        for (int k = 0; k < 32; ++k) {
            float4 a4 = *(const float4*)&Ash[k * 68 + ty * 4];
            float4 b4 = *(const float4*)&Bsh[k * 68 + tx * 4];
            float av[4] = {a4.x, a4.y, a4.z, a4.w};
            float bv[4] = {b4.x, b4.y, b4.z, b4.w};
            #pragma unroll
            for (int i = 0; i < 4; ++i)
                #pragma unroll
                for (int j = 0; j < 4; ++j)
                    acc[i][j] += av[i] * bv[j];
        }
        __syncthreads();
    }

    const int ncol = bn * 64 + tx * 4;
    float4 bias = *(const float4*)(b_ih + ncol);
    #pragma unroll
    for (int i = 0; i < 4; ++i) {
        int b = ty * 4 + i;
        float4 v;
        v.x = acc[i][0] + bias.x; v.y = acc[i][1] + bias.y;
        v.z = acc[i][2] + bias.z; v.w = acc[i][3] + bias.w;
        *(float4*)(xw + ((size_t)bm * B_SZ + b) * H_DIM + ncol) = v;
    }
}

// =====================================================================
// Kernel 2: persistent MFMA recurrence — R12 sentinel protocol + UNTAGGED
// PACKED h exchange (2 bf16 / u32) + per-wave gating.
//  Correctness linchpin (was implicit in R12, now load-bearing):
//  producer __syncthreads emits s_waitcnt vmcnt(0) before s_barrier, so
//  ALL h stores are acked at the MALL before tid0's sentinel store
//  issues. A consumer observing sent >= t therefore reads fresh h — no
//  per-word tags needed. Halves the fetch (4 KB/wave) and eliminates the
//  unpack stage (loaded u64s are already contiguous bf16 columns ->
//  direct ds_write_b64). Ring overwrite-safety: sentinel chain enforces
//  group lockstep (overwrite at t+3 requires all blocks past t+2 > any
//  reader of slot t-1). Replay safety: sent memset per call; data gated
//  by sentinel, not content. Per-wave poll: wave w waits only on its 8
//  producers (js=8w..8w+7).
// =====================================================================
__global__ __launch_bounds__(256, 1) void elman_recur_kernel(
    const float* __restrict__ xw,            // [tc][64][1024]
    const unsigned short* __restrict__ Whi,  // [1024][1024] bf16 hi plane
    const unsigned short* __restrict__ Wlo,  // [1024][1024] bf16 lo plane
    unsigned int* __restrict__ hbuf,         // [RING][64][512] packed 2xbf16
    unsigned int* __restrict__ sent,         // [8][32] monotonic sentinels
    float* __restrict__ out,                 // [64][512][1024]
    int t0, int tc)
{
    extern __shared__ __align__(16) short smem[];
    short* hA  = smem;                        // [8][HROW] bf16 (single plane)
    float* red = (float*)(smem + RED_OFF);    // [4][2][16][16]

    const int tid = threadIdx.x;
    const int bg  = blockIdx.x & 7;     // batch group
    const int js  = blockIdx.x >> 3;    // j slice
    const int w   = tid >> 6;           // wave id (K-split)
    const int l   = tid & 63;           // lane
    const int b   = tid & 7;            // epilogue: batch
    const int jl  = tid >> 3;           // epilogue: local j (0..31)
    const int jg  = js * 32 + jl;
    const int bgl = bg * 8 + b;

    // ---- one-time: W B-fragments into registers (k-contiguous, B^T layout) ----
    short8 Bhi[2][8], Blo[2][8];
    {
        const int n  = l & 15;
        const int kb = (l >> 4) * 8;
        #pragma unroll
        for (int t2 = 0; t2 < 2; ++t2) {
            const unsigned short* rhi = Whi + (size_t)(js * 32 + t2 * 16 + n) * H_DIM;
            const unsigned short* rlo = Wlo + (size_t)(js * 32 + t2 * 16 + n) * H_DIM;
            #pragma unroll
            for (int ks = 0; ks < 8; ++ks) {
                int k = w * 256 + ks * 32 + kb;
                Bhi[t2][ks] = *(const short8*)(rhi + k);
                Blo[t2][ks] = *(const short8*)(rlo + k);
            }
        }
    }

    for (int s = 0; s < tc; ++s) {
        const int t = t0 + s;

        // prefetch xw (independent of h) before any waiting
        float pre = xw[((size_t)s * B_SZ + bgl) * H_DIM + jg];

        if (t > 0) {
            // ---- per-wave sentinel poll: only MY 8 producers (js=8w..8w+7) ----
            {
                const unsigned want = (unsigned)t;   // producers at t-1 wrote t
                const unsigned* sgrp = sent + bg * 32 + w * 8;
                for (;;) {
                    unsigned sv = __hip_atomic_load(sgrp + (l & 7), __ATOMIC_RELAXED,
                                                    __HIP_MEMORY_SCOPE_AGENT);
                    if (__all((int)(sv >= want))) break;
                }
            }

            // ---- single fetch of my K-slice: 8 rows x 64 u64 = 4 KB/wave,
            //      one u64 (4 packed bf16 cols) per lane per row ----
            const unsigned long long* grp = (const unsigned long long*)
                (hbuf + (size_t)((t - 1) & (RING - 1)) * B_SZ * 512
                      + (size_t)bg * 8 * 512);
            unsigned long long v[8];
            #pragma unroll
            for (int p = 0; p < 8; ++p)
                v[p] = __hip_atomic_load(grp + p * 256 + w * 64 + l,
                                         __ATOMIC_RELAXED,
                                         __HIP_MEMORY_SCOPE_AGENT);

            // ---- direct stage to LDS: packed words ARE contiguous bf16 cols ----
            #pragma unroll
            for (int p = 0; p < 8; ++p)
                *(unsigned long long*)(hA + p * HROW + w * 256 + l * 4) = v[p];
            // no block barrier: each wave reads only columns it wrote
            // (ds write->read ordering is wave-local via lgkmcnt)

            // ---- MFMA: this wave's K range, 2 N-tiles, 2 passes (Whi+Wlo) ----
            f32x4 acc0 = {0.f, 0.f, 0.f, 0.f};
            f32x4 acc1 = {0.f, 0.f, 0.f, 0.f};
            const short* aAb = hA + (l & 7) * HROW + w * 256 + ((l >> 4) * 8);
            #pragma unroll
            for (int ks = 0; ks < 8; ++ks) {
                short8 ah = *(const short8*)(aAb + ks * 32);
                acc0 = __builtin_amdgcn_mfma_f32_16x16x32_bf16(ah, Bhi[0][ks], acc0, 0, 0, 0);
                acc1 = __builtin_amdgcn_mfma_f32_16x16x32_bf16(ah, Bhi[1][ks], acc1, 0, 0, 0);
                acc0 = __builtin_amdgcn_mfma_f32_16x16x32_bf16(ah, Blo[0][ks], acc0, 0, 0, 0);
                acc1 = __builtin_amdgcn_mfma_f32_16x16x32_bf16(ah, Blo[1][ks], acc1, 0, 0, 0);
            }
            // partials -> LDS  (D layout: col = l&15, row = (l>>4)*4 + reg)
            *(f32x4*)&red[((w * 2 + 0) * 16 + (l & 15)) * 16 + (l >> 4) * 4] = acc0;
            *(f32x4*)&red[((w * 2 + 1) * 16 + (l & 15)) * 16 + (l >> 4) * 4] = acc1;
            __syncthreads();   // B2: all waves' partials visible

            // reduce 4 wave-partials for this thread's (b, jl)
            const int tt = jl >> 4, c = jl & 15;
            #pragma unroll
            for (int w2 = 0; w2 < 4; ++w2)
                pre += red[((w2 * 2 + tt) * 16 + c) * 16 + b];
        }

        float hval = tanhf(pre);

        // ---- publish: pack 2 bf16 per u32 via wave shuffle; even-jl lanes
        //      store (half the words, same info). sc1 -> MALL. ----
        unsigned hb = (unsigned)f2bf_rn(hval);
        unsigned pb = (unsigned)__shfl_down((int)hb, 8, 64);  // partner jl+1 (same b)
        if (((l >> 3) & 1) == 0) {
            unsigned packed = hb | (pb << 16);
            __hip_atomic_store(hbuf + (size_t)(t & (RING - 1)) * B_SZ * 512
                                    + (size_t)bgl * 512 + (js * 16 + (jl >> 1)),
                               packed, __ATOMIC_RELAXED, __HIP_MEMORY_SCOPE_AGENT);
        }
        __builtin_nontemporal_store(hval, out + ((size_t)bgl * T_SEQ + t) * H_DIM + jg);

        // sentinel AFTER the barrier: __syncthreads drains vmcnt(0), so all
        // h stores are MALL-acked before the sentinel becomes visible.
        __syncthreads();
        if (tid == 0)
            __hip_atomic_store(sent + bg * 32 + js, (unsigned)(t + 1),
                               __ATOMIC_RELAXED, __HIP_MEMORY_SCOPE_AGENT);
    }
}

// =====================================================================
extern "C" void kernel_launch(void* const* d_in, const int* in_sizes, int n_in,
                              void* d_out, int out_size, void* d_ws, size_t ws_size,
                              hipStream_t stream) {
    (void)in_sizes; (void)n_in; (void)out_size;
    const float* input = (const float*)d_in[0];   // [64,512,512]
    const float* W_ih  = (const float*)d_in[1];   // [1024,512]
    const float* b_ih  = (const float*)d_in[2];   // [1024]
    const float* W_hh  = (const float*)d_in[3];   // [1024,1024]
    float* out = (float*)d_out;

    char* ws = (char*)d_ws;
    // layout: hbuf ring 512K (+pad) | sent 64K | Whh hi 2M | Whh lo 2M |
    //         Wih hi 1M | Wih lo 1M | xw ...
    unsigned int*   hbuf   = (unsigned int*)ws;
    unsigned int*   sent   = (unsigned int*)(ws + (1 << 20));
    unsigned short* Whh_hi = (unsigned short*)(ws + (1 << 20) + (64 << 10));
    unsigned short* Whh_lo = (unsigned short*)(ws + (3 << 20) + (64 << 10));
    unsigned short* Wih_hi = (unsigned short*)(ws + (5 << 20) + (64 << 10));
    unsigned short* Wih_lo = (unsigned short*)(ws + (6 << 20) + (64 << 10));
    const size_t    xw_off = (size_t)(7 << 20) + (64 << 10);
    float*          xwbuf  = (float*)(ws + xw_off);

    const size_t slice_bytes = (size_t)B_SZ * H_DIM * sizeof(float);  // 256 KB/t
    size_t avail = ws_size > xw_off ? ws_size - xw_off : 0;
    int Tc = (int)(avail / slice_bytes);
    if (Tc > T_SEQ) Tc = T_SEQ;
    bool mfma_xw = (Tc >= 128);
    if (mfma_xw) Tc &= ~127;          // multiple of 128 for the tiled GEMM
    if (Tc < 1)  Tc = 1;

    hipFuncSetAttribute((const void*)elman_recur_kernel,
                        hipFuncAttributeMaxDynamicSharedMemorySize,
                        RECUR_LDS_BYTES);

    // per-call: reset sentinels (data is sentinel-gated; replays re-gate)
    hipMemsetAsync(sent, 0, 8 * 32 * sizeof(unsigned int), stream);

    // one-time splits (stream-ordered)
    wsplit_kernel<<<dim3(4096), dim3(256), 0, stream>>>(
        W_hh, Whh_hi, Whh_lo, H_DIM * H_DIM);
    wsplit_kernel<<<dim3(2048), dim3(256), 0, stream>>>(
        W_ih, Wih_hi, Wih_lo, H_DIM * I_DIM);

    for (int t0 = 0; t0 < T_SEQ; t0 += Tc) {
        int tc = (T_SEQ - t0 < Tc) ? (T_SEQ - t0) : Tc;

        if (mfma_xw && (tc % 128) == 0) {
            int ntch = tc / 128;
            xw_mfma_kernel<<<dim3(8 * 64 * ntch), dim3(256), 0, stream>>>(
                input, Wih_hi, Wih_lo, b_ih, xwbuf, t0, ntch);
        } else {
            xw_gemm_kernel<<<dim3((unsigned)tc * 16), dim3(256), 0, stream>>>(
                input, W_ih, b_ih, xwbuf, t0);
        }

        // plain launch (graph-capture-safe, proven): 148 KB LDS -> 1 block/CU,
        // grid 256 == CU count -> co-resident.
        elman_recur_kernel<<<dim3(256), dim3(256), RECUR_LDS_BYTES, stream>>>(
            xwbuf, Whh_hi, Whh_lo, hbuf, sent, out, t0, tc);
    }
}